// Round 8
// baseline (1397.119 us; speedup 1.0000x reference)
//
#include <hip/hip_runtime.h>
#include <hip/hip_bf16.h>

// SwiGLU FFN, fp32 in/out: out = clamp(silu(x@w1t) * (x@w3t), ±65504) @ w2t
// x[8192,3072], w13[16384,3072] (rows 0..8191 = w3 -> x3, 8192.. = w1 -> x1), w2[3072,8192].
// bf16 compute via cvt pre-pass; mfma_f32_16x16x32_bf16; fp32 accum; fp32 out.
// Round-8: gateup shrunk to 128x128 so it fits the PROVEN down11 skeleton:
//   1 phase / 1 barrier / K-tile, 3-buf LDS (depth-2 prefetch), counted VMCNT(6),
//   stage tile c+2 into buffer of tile c-1 after the barrier. 67% MfmaUtil recipe.
// 16x16x32 frags + row&7 slot swizzle (2-way LDS aliasing = free, 0 conflicts).
// Swizzle rule #21: pre-swizzled global source + linear gload_lds dest + swizzled ds_read.

typedef __attribute__((ext_vector_type(8))) __bf16 bf16x8;
typedef __attribute__((ext_vector_type(4))) float f32x4;

#define GLD_LDS16(gptr, lptr)                                                        \
  __builtin_amdgcn_global_load_lds(                                                  \
      (const __attribute__((address_space(1))) void*)(gptr),                         \
      (__attribute__((address_space(3))) void*)(lptr), 16, 0, 0)

#define VMCNT(n) asm volatile("s_waitcnt vmcnt(" #n ")" ::: "memory")
#define BAR()    __builtin_amdgcn_s_barrier()

#define MFMA16(a, b, c) __builtin_amdgcn_mfma_f32_16x16x32_bf16((a), (b), (c), 0, 0, 0)

__device__ __forceinline__ __bf16 bfr(float f) {  // RNE fp32->bf16
  unsigned int u = __builtin_bit_cast(unsigned int, f);
  unsigned short r = (unsigned short)((u + 0x7FFFu + ((u >> 16) & 1u)) >> 16);
  return __builtin_bit_cast(__bf16, r);
}

// ---------------- fp32 -> bf16 conversion pre-pass ----------------
__global__ __launch_bounds__(256)
void k_cvt(const float* __restrict__ src, unsigned short* __restrict__ dst, long n) {
  long i = ((long)blockIdx.x * 256 + threadIdx.x) * 8;
  const long stride = (long)gridDim.x * 256 * 8;
  for (; i < n; i += stride) {
    float4 f0 = *(const float4*)(src + i);
    float4 f1 = *(const float4*)(src + i + 4);
    bf16x8 o;
    o[0] = bfr(f0.x); o[1] = bfr(f0.y); o[2] = bfr(f0.z); o[3] = bfr(f0.w);
    o[4] = bfr(f1.x); o[5] = bfr(f1.y); o[6] = bfr(f1.z); o[7] = bfr(f1.w);
    *(bf16x8*)(dst + i) = o;
  }
}

// ============ Kernel 1: fused gate/up, 128x128 g-tile, BK=64, 3-buf, 1 phase/K-tile ====
// 8 waves (2M x 4N), per-wave 64 rows x (32 B3-cols + 32 B1-cols). 16x16x32 frags.
// Per K-tile: VMCNT(6); BAR; rd 8 A + 4 B3 + 4 B1 frags; stage c+2 (6 loads);
//             prio1; 16 MFMA acc3 + 16 MFMA acc1; prio0.
__global__ __launch_bounds__(512, 2)
void k_gateup14(const unsigned short* __restrict__ X,
                const unsigned short* __restrict__ W13,
                __hip_bfloat16* __restrict__ G)
{
  constexpr int K = 3072, LDG = 8192, NT = K / 64;
  __shared__ unsigned short lds[73728];  // 144KB: 3 bufs x (A[128][64] | B3[128][64] | B1[128][64])
                                         // buf stride 24576 shorts; A@0, B3@8192, B1@16384

  const int t = threadIdx.x, l = t & 63, wid = t >> 6;
  const int wm = wid >> 2, wn = wid & 3;          // 2M x 4N
  const int l15 = l & 15, lhi = l >> 4, sw = l15 & 7;

  const int bid = blockIdx.x;                     // 4096 blocks, XCD-chunked (4096 = 8*512)
  const int swz = (bid & 7) * 512 + (bid >> 3);
  const int mb = swz >> 6, nb = swz & 63;

  const int srow = t >> 3;                        // 0..63
  const int scol = ((t & 7) ^ (srow & 7)) * 8;    // pre-swizzled global slot
  const unsigned short* xa = X   + (size_t)(mb * 128 + srow) * K + scol;
  const unsigned short* b3 = W13 + (size_t)(nb * 128 + srow) * K + scol;
  const unsigned short* b1 = W13 + (size_t)(8192 + nb * 128 + srow) * K + scol;
  const int lo = t * 8;

#define GST_A(e, kt) do {                                                       \
    GLD_LDS16(xa + (kt),                  lds + (e) * 24576 + lo);              \
    GLD_LDS16(xa + (size_t)64 * K + (kt),  lds + (e) * 24576 + 4096 + lo);      \
  } while (0)
#define GST_B3(e, kt) do {                                                      \
    GLD_LDS16(b3 + (kt),                  lds + (e) * 24576 + 8192 + lo);       \
    GLD_LDS16(b3 + (size_t)64 * K + (kt),  lds + (e) * 24576 + 12288 + lo);     \
  } while (0)
#define GST_B1(e, kt) do {                                                      \
    GLD_LDS16(b1 + (kt),                  lds + (e) * 24576 + 16384 + lo);      \
    GLD_LDS16(b1 + (size_t)64 * K + (kt),  lds + (e) * 24576 + 20480 + lo);     \
  } while (0)

  f32x4 acc3[4][2], acc1[4][2];
#pragma unroll
  for (int m = 0; m < 4; ++m)
#pragma unroll
    for (int n = 0; n < 2; ++n) {
      acc3[m][n] = (f32x4){0.f, 0.f, 0.f, 0.f};
      acc1[m][n] = (f32x4){0.f, 0.f, 0.f, 0.f};
    }

  // prologue: tiles 0,1 (6 loads each)
  GST_A(0, 0);  GST_B3(0, 0);  GST_B1(0, 0);
  GST_A(1, 64); GST_B3(1, 64); GST_B1(1, 64);

  for (int c = 0; c < NT; ++c) {
    const int e = c % 3;
    const int eS = (c + 2) % 3;                    // buffer of tile c-1 (reads retired)
    const int k2 = (c + 2 < NT ? c + 2 : 0) * 64;  // wrap keeps load count uniform
    const int Ab = e * 24576, B3b = Ab + 8192, B1b = Ab + 16384;

    VMCNT(6);    // tile c's 6 landed (tile c+1's 6 in flight)
    BAR();

    bf16x8 ra[4][2], r3[2][2], r1[2][2];
#pragma unroll
    for (int mf = 0; mf < 4; ++mf)
#pragma unroll
      for (int kk = 0; kk < 2; ++kk) {
        const int row = wm * 64 + mf * 16 + l15;
        ra[mf][kk] = *(const bf16x8*)(lds + Ab + row * 64 + ((kk * 4 + lhi) ^ sw) * 8);
      }
#pragma unroll
    for (int nf = 0; nf < 2; ++nf)
#pragma unroll
      for (int kk = 0; kk < 2; ++kk) {
        const int row = wn * 32 + nf * 16 + l15;
        r3[nf][kk] = *(const bf16x8*)(lds + B3b + row * 64 + ((kk * 4 + lhi) ^ sw) * 8);
        r1[nf][kk] = *(const bf16x8*)(lds + B1b + row * 64 + ((kk * 4 + lhi) ^ sw) * 8);
      }

    // stage tile c+2 into buffer of tile c-1 (safe: its reads retired before this BAR)
    GST_A(eS, k2); GST_B3(eS, k2); GST_B1(eS, k2);

    __builtin_amdgcn_s_setprio(1);
#pragma unroll
    for (int mf = 0; mf < 4; ++mf)
#pragma unroll
      for (int nf = 0; nf < 2; ++nf)
#pragma unroll
        for (int kk = 0; kk < 2; ++kk) {
          acc3[mf][nf] = MFMA16(ra[mf][kk], r3[nf][kk], acc3[mf][nf]);
          acc1[mf][nf] = MFMA16(ra[mf][kk], r1[nf][kk], acc1[mf][nf]);
        }
    __builtin_amdgcn_s_setprio(0);
  }

  // epilogue: g = clamp(silu(x1)*x3). 16x16 C/D: col=l15, row=lhi*4+r
  const int gr0 = mb * 128 + wm * 64;
  const int gc0 = nb * 128 + wn * 32;
#pragma unroll
  for (int mf = 0; mf < 4; ++mf)
#pragma unroll
    for (int nf = 0; nf < 2; ++nf)
#pragma unroll
      for (int r = 0; r < 4; ++r) {
        float h3 = acc3[mf][nf][r];
        float h1 = acc1[mf][nf][r];
        float s  = h1 / (1.f + __expf(-h1));
        float g  = fminf(fmaxf(s * h3, -65504.f), 65504.f);
        G[(size_t)(gr0 + mf * 16 + lhi * 4 + r) * LDG + (gc0 + nf * 16 + l15)] =
            __float2bfloat16(g);
      }
#undef GST_A
#undef GST_B3
#undef GST_B1
}

// ============ Kernel 2: down proj, 256x128 tile, BK=64, 3-buf, 1 phase/K-tile ============
// 8 waves (4M x 2N), per-wave 64x64, 16x16x32 frags. Proven 67% MfmaUtil — unchanged.
__global__ __launch_bounds__(512, 2)
void k_down11(const unsigned short* __restrict__ Gm,
              const unsigned short* __restrict__ W2,
              float* __restrict__ Out)
{
  constexpr int K = 8192, LDO = 3072, NT = K / 64;
  __shared__ unsigned short lds[73728];  // 144KB: A[3]@0 (16384 ea) | B[3]@49152 (8192 ea)

  const int t = threadIdx.x, l = t & 63, wid = t >> 6;
  const int wm = wid >> 1, wn = wid & 1;          // 4M x 2N
  const int l15 = l & 15, lhi = l >> 4, sw = l15 & 7;

  const int bid = blockIdx.x;                     // 768 blocks
  const int swz = (bid & 7) * 96 + (bid >> 3);
  const int mb = swz / 24, nb = swz % 24;

  const int srow = t >> 3;
  const int scol = ((t & 7) ^ (srow & 7)) * 8;
  const unsigned short* ga = Gm + (size_t)(mb * 256 + srow) * K + scol;
  const unsigned short* wb = W2 + (size_t)(nb * 128 + srow) * K + scol;
  const int lo = t * 8;

#define DST_A(e, kt) do {                                                       \
    GLD_LDS16(ga + (kt),                 lds + (e) * 16384 + lo);               \
    GLD_LDS16(ga + (size_t)64 * K + (kt),  lds + (e) * 16384 + 4096 + lo);      \
    GLD_LDS16(ga + (size_t)128 * K + (kt), lds + (e) * 16384 + 8192 + lo);      \
    GLD_LDS16(ga + (size_t)192 * K + (kt), lds + (e) * 16384 + 12288 + lo);     \
  } while (0)
#define DST_B(e, kt) do {                                                       \
    GLD_LDS16(wb + (kt),                lds + 49152 + (e) * 8192 + lo);         \
    GLD_LDS16(wb + (size_t)64 * K + (kt), lds + 49152 + (e) * 8192 + 4096 + lo); \
  } while (0)

  f32x4 acc[4][4];
#pragma unroll
  for (int mf = 0; mf < 4; ++mf)
#pragma unroll
    for (int nf = 0; nf < 4; ++nf)
      acc[mf][nf] = (f32x4){0.f, 0.f, 0.f, 0.f};

  // prologue: tiles 0,1 (6 loads each)
  DST_B(0, 0);  DST_A(0, 0);
  DST_B(1, 64); DST_A(1, 64);

  for (int c = 0; c < NT; ++c) {
    const int e = c % 3;
    const int eS = (c + 2) % 3;
    const int k2 = (c + 2 < NT ? c + 2 : 0) * 64;

    VMCNT(6);    // tile c's 6 landed (tile c+1's 6 in flight)
    BAR();

    bf16x8 ra[4][2], rb[4][2];
#pragma unroll
    for (int mf = 0; mf < 4; ++mf)
#pragma unroll
      for (int kk = 0; kk < 2; ++kk)
        ra[mf][kk] = *(const bf16x8*)(lds + e * 16384 + (wm * 64 + mf * 16 + l15) * 64 + ((kk * 4 + lhi) ^ sw) * 8);
#pragma unroll
    for (int nf = 0; nf < 4; ++nf)
#pragma unroll
      for (int kk = 0; kk < 2; ++kk)
        rb[nf][kk] = *(const bf16x8*)(lds + 49152 + e * 8192 + (wn * 64 + nf * 16 + l15) * 64 + ((kk * 4 + lhi) ^ sw) * 8);

    // stage tile c+2 into buffer of tile c-1 (reads done before this iter's barrier)
    DST_B(eS, k2);
    DST_A(eS, k2);

    __builtin_amdgcn_s_setprio(1);
#pragma unroll
    for (int mf = 0; mf < 4; ++mf)
#pragma unroll
      for (int nf = 0; nf < 4; ++nf)
#pragma unroll
        for (int kk = 0; kk < 2; ++kk)
          acc[mf][nf] = MFMA16(ra[mf][kk], rb[nf][kk], acc[mf][nf]);
    __builtin_amdgcn_s_setprio(0);
  }

  const int r0 = mb * 256 + wm * 64;
  const int c0 = nb * 128 + wn * 64;
#pragma unroll
  for (int mf = 0; mf < 4; ++mf)
#pragma unroll
    for (int nf = 0; nf < 4; ++nf)
#pragma unroll
      for (int r = 0; r < 4; ++r)
        Out[(size_t)(r0 + mf * 16 + lhi * 4 + r) * LDO + (c0 + nf * 16 + l15)] =
            acc[mf][nf][r];
#undef DST_A
#undef DST_B
}

extern "C" void kernel_launch(void* const* d_in, const int* in_sizes, int n_in,
                              void* d_out, int out_size, void* d_ws, size_t ws_size,
                              hipStream_t stream) {
  const float* x   = (const float*)d_in[0];   // [2,4096,3072] f32
  const float* w13 = (const float*)d_in[1];   // [16384,3072] f32
  const float* w2  = (const float*)d_in[2];   // [3072,8192] f32
  float* out = (float*)d_out;                 // [2,4096,3072] f32

  const long NX = 25165824L, NW13 = 50331648L, NW2 = 25165824L;
  const size_t XB = 50331648, W13B = 100663296, W2B = 50331648;

  unsigned short* xb   = (unsigned short*)d_ws;
  unsigned short* w13b = (unsigned short*)((char*)d_ws + XB);
  unsigned short* w2b  = (unsigned short*)((char*)d_ws + XB + W13B);
  __hip_bfloat16* g    = (__hip_bfloat16*)((char*)d_ws + XB + W13B + W2B);

  k_cvt<<<2048, 256, 0, stream>>>(x,   xb,   NX);
  k_cvt<<<2048, 256, 0, stream>>>(w13, w13b, NW13);
  k_cvt<<<2048, 256, 0, stream>>>(w2,  w2b,  NW2);
  k_gateup14<<<4096, 512, 0, stream>>>(xb, w13b, g);
  k_down11<<<768, 512, 0, stream>>>((const unsigned short*)g, w2b, out);
}